// Round 23
// baseline (15059.119 us; speedup 1.0000x reference)
//
#include <hip/hip_runtime.h>
#include <math.h>

// VanillaRNN B=256,T=512,H=1024,O=10 — bit-exact replication of reference CPU
// fp32 trajectory. Decoded arithmetic (R5-R7 oracle): kc=512 panels, no-FMA
// chains (__fmul_rn/__fadd_rn, k ascending, panels joined in order), tanh =
// clamp ±7.99881172180175781 + fmaf Horner + IEEE div, no-FMA xp.
//
// R22 = R21 with the bank-conflict actually fixed + 4 waves/SIMD:
//  - R21's [c][k] XOR layout had unavoidable 4-way conflicts with 32 unique
//    cols/wave (pigeonhole on 8 bank-starts; SQ_LDS_BANK_CONFLICT 1.075e9).
//  - New wave geometry: 8 cols x 8 rows per wave (lane = c8 + 8*r8). Only 8
//    unique W addresses per b128; bank-starts {k4^4m} cover all 32 banks
//    exactly once -> conflict-free, 8-way broadcast free.
//  - NTH 1024 (16 waves, 4/SIMD; thread = 1 row x 1 col): 2x latency hiding
//    vs R20/R21. 16 waves = 4x4 blocks of 8x8 over the 32x32 (row,col) tile.
//  - W slice [32 cols][1024 k] swizzled, 128 KB LDS, loaded once (R21 preload
//    verbatim). Grid 256 = 8 XCD-local groups x 32 cts. De-poisoned sync.
//  - Chain contract unchanged: a=panel0 k-ascending, b=panel1, m=fadd(a,b),
//    no-FMA xp, verbatim tanh, ordered join.

#define HH 1024
#define TT 512
#define BB 256
#define OO 10
#define NGRP 8     // row groups (32 rows) = XCDs
#define NCT 32     // col tiles (32 cols)
#define NTH 1024
#define KH 512     // panel size

__device__ __forceinline__ float tanh_ref(float x) {
    const float kClamp = 7.99881172180175781f;
    float xc = fminf(fmaxf(x, -kClamp), kClamp);
    float x2 = __fmul_rn(xc, xc);
    float p = -2.76076847742355e-16f;
    p = fmaf(x2, p,  2.00018790482477e-13f);
    p = fmaf(x2, p, -8.60467152213735e-11f);
    p = fmaf(x2, p,  5.12229709037114e-08f);
    p = fmaf(x2, p,  1.48572235717979e-05f);
    p = fmaf(x2, p,  6.37261928875436e-04f);
    p = fmaf(x2, p,  4.89352455891786e-03f);
    p = __fmul_rn(xc, p);
    float q = 1.19825839466702e-06f;
    q = fmaf(x2, q, 1.18534705686654e-04f);
    q = fmaf(x2, q, 2.26843463243900e-03f);
    q = fmaf(x2, q, 4.89352518554385e-03f);
    float r = __fdiv_rn(p, q);
    return (fabsf(x) < 0.0004f) ? x : r;
}

#define MACC(acc, hv, wv) acc = __fadd_rn(acc, __fmul_rn(hv, wv))

// De-poisoned row-group sync (R17-proven): relaxed agent atomics, producer
// drain via __syncthreads (vmcnt 0), consumer vL1-only buffer_inv. Group is
// XCD-local (bid&7) => its L2 is the common coherence point.
#define GROUPSYNC_FAST(target_) {                                                   \
    __syncthreads();                                                                 \
    if (tid == 0) {                                                                  \
        __hip_atomic_fetch_add(&ctr[g], 1, __ATOMIC_RELAXED, __HIP_MEMORY_SCOPE_AGENT); \
        while (__hip_atomic_load(&ctr[g], __ATOMIC_RELAXED, __HIP_MEMORY_SCOPE_AGENT)   \
               < (target_))                                                          \
            __builtin_amdgcn_s_sleep(2);                                             \
    }                                                                                \
    __syncthreads();                                                                 \
    asm volatile("buffer_inv" ::: "memory");                                         \
}

__global__ void __launch_bounds__(NTH, 1) rnn_persist(
    const float* __restrict__ x, const float* __restrict__ Whx,
    const float* __restrict__ Whh, const float* __restrict__ Wph,
    const float* __restrict__ bh, const float* __restrict__ bo,
    float* __restrict__ out, float* __restrict__ ws)
{
    __shared__ float wldsT[32][1024];   // 128 KB: col-major W slice, k XOR-swizzled

    const int bid  = blockIdx.x;        // 0..255
    const int g    = bid & 7;           // row group == XCD
    const int ct   = bid >> 3;          // col tile 0..31
    const int tid  = threadIdx.x;
    const int w    = tid >> 6;          // wave 0..15
    const int lane = tid & 63;
    const int c8   = lane & 7;          // col within wave's 8-col block
    const int r8   = lane >> 3;         // row within wave's 8-row block
    const int c32  = (w & 3) * 8 + c8;  // col within 32-col tile
    const int row_l= (w >> 2) * 8 + r8; // row within 32-row group
    const int j0   = ct * 32;
    const int j    = j0 + c32;          // this thread's column
    const int row  = g * 32 + row_l;    // this thread's (single) row
    const int swz  = (c32 & 7) << 2;    // XOR swizzle (bits 2..4)

    float* hAbuf = ws;                  // [256][1024]
    float* hBbuf = ws + (BB * HH);
    int*   ctr   = (int*)(ws + 2 * BB * HH);  // [8], memset 0 pre-launch

    const float whx_j = Whx[j];
    const float bh_j  = bh[j];

    // ---- one-time W preload into transposed+swizzled layout (R21 verbatim) ----
    #pragma unroll
    for (int i = 0; i < 32; ++i) {
        const int e = tid + i * NTH;     // 0..32767
        const int k = e >> 5;            // 0..1023
        const int c = e & 31;
        wldsT[c][k ^ ((c & 7) << 2)] = Whh[(size_t)k * HH + j0 + c];
    }

    // ---- zero-init hA row, then group sync ----
    hAbuf[(size_t)row * HH + j] = 0.0f;
    GROUPSYNC_FAST(NCT)

    for (int t = 0; t < TT; ++t) {
        const float* hsrc = (t & 1) ? hBbuf : hAbuf;
        float*       hdst = (t & 1) ? hAbuf : hBbuf;

        const float* hp = hsrc + (size_t)row * HH;
        const float* wrow = wldsT[c32];

        float a = 0.f;   // panel0 chain
        float b = 0.f;   // panel1 chain

        #pragma unroll 4
        for (int k4 = 0; k4 < KH; k4 += 4) {
            const float4 ha = *(const float4*)(hp + k4);
            const float4 hb = *(const float4*)(hp + KH + k4);
            // W via swizzled b128: 8 unique addrs/wave -> all 32 banks once
            const float4 w4 = *(const float4*)(wrow + (k4 ^ swz));
            const float4 v4 = *(const float4*)(wrow + ((KH + k4) ^ swz));
            // k ascending per panel — chain order is the correctness contract
            MACC(a, ha.x, w4.x); MACC(b, hb.x, v4.x);
            MACC(a, ha.y, w4.y); MACC(b, hb.y, v4.y);
            MACC(a, ha.z, w4.z); MACC(b, hb.z, v4.z);
            MACC(a, ha.w, w4.w); MACC(b, hb.w, v4.w);
        }

        // join panels (p0 then p1), xp, z, tanh, store (contract order)
        {
            const float m = __fadd_rn(a, b);
            const float xv = x[(size_t)row * TT + t];
            hdst[(size_t)row * HH + j] =
                tanh_ref(__fadd_rn(__fadd_rn(__fmul_rn(xv, whx_j), bh_j), m));
        }

        GROUPSYNC_FAST(NCT * (t + 2))
    }

    // ---- epilogue: out = h_final @ Wph + bo (h_final in hAbuf; TT even) ----
    if (ct == 0) {
        #pragma unroll 1
        for (int p = w; p < 32 * OO; p += 16) {
            const int rr = p / OO, o = p % OO;
            const int orow = g * 32 + rr;
            float v = 0.0f;
            #pragma unroll
            for (int m = 0; m < HH / 64; ++m) {
                const int k = lane + (m << 6);
                v = fmaf(hAbuf[(size_t)orow * HH + k], Wph[k * OO + o], v);
            }
            #pragma unroll
            for (int s = 32; s > 0; s >>= 1) v += __shfl_down(v, s, 64);
            if (lane == 0) out[orow * OO + o] = v + bo[o];
        }
    }
}

extern "C" void kernel_launch(void* const* d_in, const int* in_sizes, int n_in,
                              void* d_out, int out_size, void* d_ws, size_t ws_size,
                              hipStream_t stream) {
    const float* x   = (const float*)d_in[0];
    const float* Whx = (const float*)d_in[1];
    const float* Whh = (const float*)d_in[2];
    const float* Wph = (const float*)d_in[3];
    const float* bh  = (const float*)d_in[4];
    const float* bo  = (const float*)d_in[5];
    float* out = (float*)d_out;
    float* ws  = (float*)d_ws;

    // reset row-group counters (8 ints at the 2 MB mark — proven region)
    hipMemsetAsync((char*)d_ws + (size_t)2 * BB * HH * 4, 0, 64, stream);

    void* args[] = {(void*)&x, (void*)&Whx, (void*)&Whh, (void*)&Wph,
                    (void*)&bh, (void*)&bo, (void*)&out, (void*)&ws};
    hipLaunchCooperativeKernel((void*)rnn_persist, dim3(NGRP * NCT), dim3(NTH),
                               args, 0, stream);
}